// Round 1
// baseline (33927.679 us; speedup 1.0000x reference)
//
#include <hip/hip_runtime.h>
#include <hip/hip_bf16.h>
#include <math.h>

// Problem constants (from reference): T=512, B=64, D=512, H=1024, O=512
constexpr int T = 512;
constexpr int B = 64;
constexpr int D = 512;
constexpr int H = 1024;
constexpr int O = 512;
constexpr int KTOT = D + H;   // 1536, fused K for [x_t | h] @ [Wx | Wh]^T

// Step-kernel tiling: block computes a [16 b x 16 j] tile, all 4 gates per thread.
constexpr int TBJ = 16;
constexpr int TBB = 16;
constexpr int KT  = 32;       // K-chunk per LDS stage
constexpr int LDP = 36;       // padded K stride: 36*4B=144B -> 16B aligned rows, bank stride 4 (2-way alias, free)

__global__ __launch_bounds__(256) void lstm_step(
    const float* __restrict__ x_t,   // [B, D]   x at this timestep
    const float* __restrict__ Wx,    // [4H, D]
    const float* __restrict__ Wh,    // [4H, H]
    const float* __restrict__ bx,    // [4H]
    const float* __restrict__ bh,    // [4H]
    const float* __restrict__ h_in,  // [B, H]
    float* __restrict__ h_out,       // [B, H]
    float* __restrict__ c_st)        // [B, H] (in-place: each element owned by one thread)
{
    __shared__ __attribute__((aligned(16))) float As[TBB][LDP];     // activations [b][k]
    __shared__ __attribute__((aligned(16))) float Ws[4][TBJ][LDP];  // weights [gate][j][k]

    const int tid = threadIdx.x;
    const int tx  = tid & 15;    // local j
    const int ty  = tid >> 4;    // local b
    const int j0  = blockIdx.x * TBJ;
    const int b0  = blockIdx.y * TBB;

    float acc0 = 0.f, acc1 = 0.f, acc2 = 0.f, acc3 = 0.f;

    for (int kk = 0; kk < KTOT; kk += KT) {
        // ---- stage A tile: 16 rows x 32 k = 128 float4; threads 0..127 ----
        if (tid < 128) {
            const int bb = tid >> 3;        // 0..15
            const int k4 = tid & 7;         // 0..7
            const int kg = kk + k4 * 4;     // KT=32 divides D, so a chunk is purely x or purely h
            float4 v;
            if (kg < D) v = *(const float4*)&x_t[(size_t)(b0 + bb) * D + kg];
            else        v = *(const float4*)&h_in[(size_t)(b0 + bb) * H + (kg - D)];
            *(float4*)&As[bb][k4 * 4] = v;
        }
        // ---- stage W tile: 4 gates x 16 j x 32 k = 512 float4; 2 per thread ----
        #pragma unroll
        for (int r = 0; r < 2; ++r) {
            const int e   = tid + r * 256;  // 0..511
            const int g   = e >> 7;         // 0..3
            const int rem = e & 127;
            const int jj  = rem >> 3;       // 0..15
            const int k4  = rem & 7;        // 0..7
            const int row = g * H + j0 + jj;
            const int kg  = kk + k4 * 4;
            float4 v;
            if (kg < D) v = *(const float4*)&Wx[(size_t)row * D + kg];
            else        v = *(const float4*)&Wh[(size_t)row * H + (kg - D)];
            *(float4*)&Ws[g][jj][k4 * 4] = v;
        }
        __syncthreads();

        #pragma unroll
        for (int k4 = 0; k4 < KT / 4; ++k4) {
            const float4 a  = *(const float4*)&As[ty][k4 * 4];
            const float4 w0 = *(const float4*)&Ws[0][tx][k4 * 4];
            const float4 w1 = *(const float4*)&Ws[1][tx][k4 * 4];
            const float4 w2 = *(const float4*)&Ws[2][tx][k4 * 4];
            const float4 w3 = *(const float4*)&Ws[3][tx][k4 * 4];
            acc0 += a.x * w0.x + a.y * w0.y + a.z * w0.z + a.w * w0.w;
            acc1 += a.x * w1.x + a.y * w1.y + a.z * w1.z + a.w * w1.w;
            acc2 += a.x * w2.x + a.y * w2.y + a.z * w2.z + a.w * w2.w;
            acc3 += a.x * w3.x + a.y * w3.y + a.z * w3.z + a.w * w3.w;
        }
        __syncthreads();
    }

    const int j = j0 + tx;
    const int b = b0 + ty;
    acc0 += bx[0 * H + j] + bh[0 * H + j];
    acc1 += bx[1 * H + j] + bh[1 * H + j];
    acc2 += bx[2 * H + j] + bh[2 * H + j];
    acc3 += bx[3 * H + j] + bh[3 * H + j];

    const float ig = 1.f / (1.f + expf(-acc0));
    const float fg = 1.f / (1.f + expf(-acc1));
    const float og = 1.f / (1.f + expf(-acc2));
    const float cg = tanhf(acc3);

    const int idx = b * H + j;
    const float cn = fg * c_st[idx] + ig * cg;
    c_st[idx]  = cn;
    h_out[idx] = og * tanhf(cn);
}

// out[b,o] = sum_k h[b,k] * Why[o,k] + bhy[o]
__global__ __launch_bounds__(256) void out_gemm(
    const float* __restrict__ h,    // [B, H]
    const float* __restrict__ Why,  // [O, H]
    const float* __restrict__ bhy,  // [O]
    float* __restrict__ out)        // [B, O]
{
    const int idx = blockIdx.x * 256 + threadIdx.x;
    if (idx >= B * O) return;
    const int b = idx / O;
    const int o = idx % O;
    const float4* hv = (const float4*)&h[(size_t)b * H];
    const float4* wv = (const float4*)&Why[(size_t)o * H];
    float s = 0.f;
    #pragma unroll 4
    for (int k = 0; k < H / 4; ++k) {
        const float4 a = hv[k];
        const float4 w = wv[k];
        s += a.x * w.x + a.y * w.y + a.z * w.z + a.w * w.w;
    }
    out[idx] = s + bhy[o];
}

extern "C" void kernel_launch(void* const* d_in, const int* in_sizes, int n_in,
                              void* d_out, int out_size, void* d_ws, size_t ws_size,
                              hipStream_t stream) {
    const float* x   = (const float*)d_in[0];  // [T, B, D]
    const float* Wx  = (const float*)d_in[1];  // [4H, D]
    const float* bx  = (const float*)d_in[2];  // [4H]
    const float* Wh  = (const float*)d_in[3];  // [4H, H]
    const float* bh  = (const float*)d_in[4];  // [4H]
    const float* Why = (const float*)d_in[5];  // [O, H]
    const float* bhy = (const float*)d_in[6];  // [O]
    float* out = (float*)d_out;

    // Workspace layout: h_ping | h_pong | c   (ws is re-poisoned 0xAA every call -> zero it)
    float* h0 = (float*)d_ws;
    float* h1 = h0 + (size_t)B * H;
    float* c  = h1 + (size_t)B * H;
    hipMemsetAsync(d_ws, 0, (size_t)3 * B * H * sizeof(float), stream);

    const dim3 grid(H / TBJ, B / TBB);  // (64, 4) = 256 blocks
    for (int t = 0; t < T; ++t) {
        const float* hin = (t & 1) ? h1 : h0;
        float*      hout = (t & 1) ? h0 : h1;
        lstm_step<<<grid, 256, 0, stream>>>(x + (size_t)t * B * D, Wx, Wh, bx, bh,
                                            hin, hout, c);
    }
    // T even -> final h lives in h0
    const float* hfin = h0;
    out_gemm<<<(B * O + 255) / 256, 256, 0, stream>>>(hfin, Why, bhy, out);
}

// Round 2
// 32518.970 us; speedup vs baseline: 1.0433x; 1.0433x over previous
//
#include <hip/hip_runtime.h>
#include <hip/hip_bf16.h>
#include <math.h>

// Problem constants: T=512, B=64, D=512, H=1024, O=512
constexpr int T = 512;
constexpr int B = 64;
constexpr int D = 512;
constexpr int H = 1024;
constexpr int O = 512;
constexpr int KTOT = D + H;   // 1536 fused K: A = [x_t | h]
constexpr int N4   = 4 * H;   // 4096 gate-major output cols, reordered n = j*4+g
constexpr int KC   = 256;     // K-chunk staged in LDS per iteration
constexpr int LDA  = KC + 8;  // padded A row stride (bf16 elems): 528 B -> balanced banks for b128 reads

typedef __attribute__((ext_vector_type(8))) __bf16 bf16x8;
typedef __attribute__((ext_vector_type(4))) float  floatx4;

// ---------------------------------------------------------------------------
// One-time per call: W' bf16 [4096][1536], rows reordered n = j*4+g so that a
// 16-wide n-strip holds 4 j's x 4 gates (epilogue fuses cell update per wave).
// k < 512 comes from Wx[g*H+j][k], else Wh[g*H+j][k-512].
// ---------------------------------------------------------------------------
__global__ __launch_bounds__(256) void convert_w(
    const float* __restrict__ Wx, const float* __restrict__ Wh,
    __bf16* __restrict__ Wc)
{
    const int total = N4 * (KTOT / 4);
    for (int id = blockIdx.x * 256 + threadIdx.x; id < total; id += gridDim.x * 256) {
        const int n  = id / (KTOT / 4);
        const int c4 = id % (KTOT / 4);
        const int k  = c4 * 4;
        const int j  = n >> 2, g = n & 3;
        float4 v;
        if (k < D) v = *(const float4*)&Wx[(size_t)(g * H + j) * D + k];
        else       v = *(const float4*)&Wh[(size_t)(g * H + j) * H + (k - D)];
        __bf16 tmp[4] = { (__bf16)v.x, (__bf16)v.y, (__bf16)v.z, (__bf16)v.w };
        *(uint2*)&Wc[(size_t)n * KTOT + k] = *(uint2*)tmp;  // 8B store, aligned
    }
}

__global__ __launch_bounds__(256) void make_bias(
    const float* __restrict__ bx, const float* __restrict__ bh,
    float* __restrict__ bias)
{
    const int n = blockIdx.x * 256 + threadIdx.x;
    if (n < N4) {
        const int j = n >> 2, g = n & 3;
        bias[n] = bx[g * H + j] + bh[g * H + j];
    }
}

// ---------------------------------------------------------------------------
// One timestep: gates[64,4096] = [x_t | h] @ W'^T via mfma_f32_16x16x32_bf16,
// fused cell update in the epilogue. Grid 128 blocks x 128 threads (2 waves).
// Wave w owns n-strip [n0, n0+16), n0 = blockIdx*32 + w*16 -> W read ONCE/step.
// A staged fp32->bf16 into LDS per K-chunk; B-frags straight from global (L2).
// ---------------------------------------------------------------------------
__global__ __launch_bounds__(128) void lstm_step_mfma(
    const float* __restrict__ x_t,   // [B, D] fp32
    const __bf16* __restrict__ Wc,   // [4096][1536] reordered bf16
    const float* __restrict__ bias,  // [4096] (bx+bh, reordered)
    const float* __restrict__ h_in,  // [B, H] fp32
    float* __restrict__ h_out,       // [B, H] fp32
    float* __restrict__ c_st)        // [B, H] fp32, in-place (owner-exclusive)
{
    __shared__ __attribute__((aligned(16))) __bf16 As[64 * LDA];   // 33.8 KB
    __shared__ __attribute__((aligned(16))) float  G[2][64][20];   // 10.2 KB, padded (80B rows)

    const int tid  = threadIdx.x;
    const int wid  = tid >> 6;
    const int lane = tid & 63;
    const int c    = lane & 15;   // n_local / m_local
    const int q    = lane >> 4;   // quad
    const int n0   = blockIdx.x * 32 + wid * 16;

    floatx4 acc[4] = {};  // 4 m-tiles: D[row = mt*16 + q*4 + reg][col = n0 + c]

    for (int kk = 0; kk < KTOT; kk += KC) {
        // ---- stage A chunk [64 x 256] fp32 -> bf16 LDS (chunks align with D boundary) ----
        for (int i = tid; i < 64 * (KC / 4); i += 128) {
            const int row = i >> 6;          // KC/4 == 64 float4-groups per row
            const int c4  = i & 63;
            const int kg  = kk + c4 * 4;
            float4 v;
            if (kg < D) v = *(const float4*)&x_t[(size_t)row * D + kg];
            else        v = *(const float4*)&h_in[(size_t)row * H + (kg - D)];
            __bf16 tmp[4] = { (__bf16)v.x, (__bf16)v.y, (__bf16)v.z, (__bf16)v.w };
            *(uint2*)&As[row * LDA + c4 * 4] = *(uint2*)tmp;
        }
        __syncthreads();

        // ---- MFMA over the chunk: 8 k-subchunks x 4 m-tiles ----
        const __bf16* wrow = &Wc[(size_t)(n0 + c) * KTOT + kk + q * 8];
        #pragma unroll
        for (int s = 0; s < KC / 32; ++s) {
            const bf16x8 bfrag = *(const bf16x8*)(wrow + s * 32);   // W'[n][k..k+8), 16B global
            #pragma unroll
            for (int mt = 0; mt < 4; ++mt) {
                const bf16x8 afrag = *(const bf16x8*)&As[(mt * 16 + c) * LDA + s * 32 + q * 8];
                acc[mt] = __builtin_amdgcn_mfma_f32_16x16x32_bf16(afrag, bfrag, acc[mt], 0, 0, 0);
            }
        }
        __syncthreads();
    }

    // ---- epilogue: transpose C through per-wave LDS, fused LSTM cell update ----
    #pragma unroll
    for (int mt = 0; mt < 4; ++mt)
        #pragma unroll
        for (int r = 0; r < 4; ++r)
            G[wid][mt * 16 + q * 4 + r][c] = acc[mt][r];
    __syncthreads();

    const int jl = lane & 3;              // j within strip (4 j's x 4 gates = 16 cols)
    const int bs = lane >> 2;             // 0..15
    const int j  = (n0 >> 2) + jl;        // global hidden index
    const float4 b4 = *(const float4*)&bias[n0 + jl * 4];  // gates i,f,o,c for this j

    #pragma unroll
    for (int r = 0; r < 4; ++r) {
        const int b = bs + r * 16;
        const float4 g4 = *(const float4*)&G[wid][b][jl * 4];
        const float ig = 1.f / (1.f + expf(-(g4.x + b4.x)));
        const float fg = 1.f / (1.f + expf(-(g4.y + b4.y)));
        const float og = 1.f / (1.f + expf(-(g4.z + b4.z)));
        const float ct = tanhf(g4.w + b4.w);
        const size_t idx = (size_t)b * H + j;
        const float cn = fg * c_st[idx] + ig * ct;
        c_st[idx]  = cn;
        h_out[idx] = og * tanhf(cn);
    }
}

// out[b,o] = h[b,:] . Why[o,:] + bhy[o]   (tiny, fp32)
__global__ __launch_bounds__(256) void out_gemm(
    const float* __restrict__ h, const float* __restrict__ Why,
    const float* __restrict__ bhy, float* __restrict__ out)
{
    const int idx = blockIdx.x * 256 + threadIdx.x;
    if (idx >= B * O) return;
    const int b = idx / O;
    const int o = idx % O;
    const float4* hv = (const float4*)&h[(size_t)b * H];
    const float4* wv = (const float4*)&Why[(size_t)o * H];
    float s = 0.f;
    #pragma unroll 4
    for (int k = 0; k < H / 4; ++k) {
        const float4 a = hv[k];
        const float4 w = wv[k];
        s += a.x * w.x + a.y * w.y + a.z * w.z + a.w * w.w;
    }
    out[idx] = s + bhy[o];
}

extern "C" void kernel_launch(void* const* d_in, const int* in_sizes, int n_in,
                              void* d_out, int out_size, void* d_ws, size_t ws_size,
                              hipStream_t stream) {
    const float* x   = (const float*)d_in[0];  // [T, B, D]
    const float* Wx  = (const float*)d_in[1];  // [4H, D]
    const float* bx  = (const float*)d_in[2];  // [4H]
    const float* Wh  = (const float*)d_in[3];  // [4H, H]
    const float* bh  = (const float*)d_in[4];  // [4H]
    const float* Why = (const float*)d_in[5];  // [O, H]
    const float* bhy = (const float*)d_in[6];  // [O]
    float* out = (float*)d_out;

    // ws layout: W' bf16 (12,582,912 B) | bias (16,384 B) | h0 | h1 | c (256 KB each)
    char*   ws   = (char*)d_ws;
    __bf16* Wc   = (__bf16*)ws;
    float*  bias = (float*)(ws + 12582912);
    float*  h0   = (float*)(ws + 12582912 + 16384);
    float*  h1   = h0 + (size_t)B * H;
    float*  c    = h1 + (size_t)B * H;

    hipMemsetAsync(h0, 0, (size_t)3 * B * H * sizeof(float), stream);
    convert_w<<<1024, 256, 0, stream>>>(Wx, Wh, Wc);
    make_bias<<<16, 256, 0, stream>>>(bx, bh, bias);

    for (int t = 0; t < T; ++t) {
        const float* hin = (t & 1) ? h1 : h0;
        float*      hout = (t & 1) ? h0 : h1;
        lstm_step_mfma<<<128, 128, 0, stream>>>(x + (size_t)t * B * D, Wc, bias,
                                                hin, hout, c);
    }
    // T even -> final h in h0
    out_gemm<<<(B * O + 255) / 256, 256, 0, stream>>>(h0, Why, bhy, out);
}

// Round 3
// 11157.298 us; speedup vs baseline: 3.0409x; 2.9146x over previous
//
#include <hip/hip_runtime.h>
#include <hip/hip_bf16.h>
#include <math.h>

// Problem constants: T=512, B=64, D=512, H=1024, O=512
constexpr int T = 512;
constexpr int B = 64;
constexpr int D = 512;
constexpr int H = 1024;
constexpr int O = 512;
constexpr int NBLK = 256;           // persistent blocks == CU count
constexpr int KCH  = (D + H) / 8;   // 192 k-chunks of 8 elems

typedef __attribute__((ext_vector_type(8))) __bf16 bf16x8;
typedef __attribute__((ext_vector_type(4))) float  floatx4;

// Barrier vars on separate 128B lines
struct GBar { unsigned int cnt; unsigned int p0[31]; unsigned int flag; unsigned int p1[31]; };

// ---------------------------------------------------------------------------
// W' bf16, strip-major for direct LDS staging: Wc[strip][kchunk][nl][8],
// strip = n/16, nl = n%16, column reorder n = j*4+g (4 j's x 4 gates / strip).
// k<512 from Wx[g*H+j][k], else Wh[g*H+j][k-512].
// ---------------------------------------------------------------------------
__global__ __launch_bounds__(256) void convert_w(
    const float* __restrict__ Wx, const float* __restrict__ Wh,
    __bf16* __restrict__ Wc)
{
    const int id = blockIdx.x * 256 + threadIdx.x;   // 4096*192 = 786432 total
    if (id >= 4096 * 192) return;
    const int nl     = id & 15;
    const int kchunk = (id >> 4) % KCH;
    const int strip  = id / (KCH * 16);
    const int n = strip * 16 + nl;
    const int j = n >> 2, g = n & 3;
    const int k0 = kchunk * 8;
    const float* src = (k0 < D) ? &Wx[(size_t)(g * H + j) * D + k0]
                                : &Wh[(size_t)(g * H + j) * H + (k0 - D)];
    const float4 a = *(const float4*)src;
    const float4 b = *(const float4*)(src + 4);
    __bf16 tmp[8] = {(__bf16)a.x,(__bf16)a.y,(__bf16)a.z,(__bf16)a.w,
                     (__bf16)b.x,(__bf16)b.y,(__bf16)b.z,(__bf16)b.w};
    *(uint4*)&Wc[(size_t)id * 8] = *(uint4*)tmp;     // coalesced 16B stores
}

__global__ __launch_bounds__(256) void make_bias(
    const float* __restrict__ bx, const float* __restrict__ bh,
    float* __restrict__ bias)
{
    const int n = blockIdx.x * 256 + threadIdx.x;
    if (n < 4 * H) {
        const int j = n >> 2, g = n & 3;
        bias[n] = bx[g * H + j] + bh[g * H + j];
    }
}

// ---------------------------------------------------------------------------
// Persistent LSTM: 256 blocks x 256 threads (4 waves). Block owns 16 gate-cols
// (4 hidden j's); W-strip lives in LDS for all 512 steps; c lives in one VGPR
// per thread; h round-trips through global bf16 with a device-scope barrier
// per step. x-part MFMAs for step t+1 are computed before waiting on the
// barrier (h-independent work hides barrier latency).
// ---------------------------------------------------------------------------
__global__ __launch_bounds__(256, 2) void lstm_persistent(
    const float* __restrict__ x,     // [T,B,D] fp32
    const __bf16* __restrict__ Wc,   // strip-major bf16
    const float* __restrict__ bias,  // [4096] reordered
    __bf16* __restrict__ hb0,        // [B,H] bf16 ping
    __bf16* __restrict__ hb1,        // [B,H] bf16 pong
    float* __restrict__ hfin,        // [B,H] fp32 final h
    GBar* bar)
{
    __shared__ __attribute__((aligned(16))) __bf16 wlds[KCH * 16 * 8]; // 48 KB
    __shared__ __attribute__((aligned(16))) float  G[64][20];          // 5 KB

    const int tid  = threadIdx.x;
    const int wid  = tid >> 6;     // wave id == m-tile
    const int lane = tid & 63;
    const int cm   = lane & 15;    // m for A-frag, n_local for B-frag
    const int q    = lane >> 4;    // k-quad
    const int n0   = blockIdx.x * 16;

    // ---- one-time: stage W strip into LDS (3072 x 16B, contiguous) ----
    {
        const uint4* wsrc = (const uint4*)(Wc + (size_t)blockIdx.x * KCH * 16 * 8);
        uint4* wdst = (uint4*)wlds;
        for (int i = tid; i < KCH * 16; i += 256) wdst[i] = wsrc[i];
    }
    // epilogue-fixed mapping: thread owns (b=eb, j=jg); c stays in a register
    const int eb = tid >> 2;
    const int jl = tid & 3;
    const int jg = (n0 >> 2) + jl;
    const float4 bias4 = *(const float4*)&bias[n0 + jl * 4];
    float c_reg = 0.f;
    __syncthreads();

    const float* xrow = x + (size_t)(wid * 16 + cm) * D + q * 8;
    const int    hoff = (wid * 16 + cm) * H + q * 8;
    const __bf16* wl  = &wlds[q * 128 + cm * 8];   // + kgroup*512

    floatx4 acc[4];

    // x-part of step tt: zero-init acc, accumulate K=0..511 (h-independent)
    auto do_xpart = [&](int tt) {
        acc[0] = (floatx4){0,0,0,0}; acc[1] = (floatx4){0,0,0,0};
        acc[2] = (floatx4){0,0,0,0}; acc[3] = (floatx4){0,0,0,0};
        const float* xr = xrow + (size_t)tt * (B * D);
        #pragma unroll
        for (int s = 0; s < 16; ++s) {
            const float4 a0 = *(const float4*)(xr + s * 32);
            const float4 a1 = *(const float4*)(xr + s * 32 + 4);
            const bf16x8 af = {(__bf16)a0.x,(__bf16)a0.y,(__bf16)a0.z,(__bf16)a0.w,
                               (__bf16)a1.x,(__bf16)a1.y,(__bf16)a1.z,(__bf16)a1.w};
            const bf16x8 bf = *(const bf16x8*)(wl + s * 512);
            acc[s & 3] = __builtin_amdgcn_mfma_f32_16x16x32_bf16(af, bf, acc[s & 3], 0, 0, 0);
        }
    };

    do_xpart(0);

    for (int t = 0; t < T; ++t) {
        const __bf16* hcur = (t & 1) ? hb1 : hb0;
        __bf16*       hnxt = (t & 1) ? hb0 : hb1;

        // ---- wait for step t-1's h to be published ----
        if (t > 0) {
            if (tid == 0) {
                while (__hip_atomic_load(&bar->flag, __ATOMIC_RELAXED,
                                         __HIP_MEMORY_SCOPE_AGENT) < (unsigned)t)
                    __builtin_amdgcn_s_sleep(1);
            }
            __syncthreads();
            __builtin_amdgcn_fence(__ATOMIC_ACQUIRE, "agent");  // invalidate stale L1/L2
        }

        // ---- h-part: K = 512..1535 ----
        const __bf16* hr = hcur + hoff;
        #pragma unroll
        for (int s = 0; s < 32; ++s) {
            const bf16x8 af = *(const bf16x8*)(hr + s * 32);
            const bf16x8 bf = *(const bf16x8*)(wl + (16 + s) * 512);
            acc[s & 3] = __builtin_amdgcn_mfma_f32_16x16x32_bf16(af, bf, acc[s & 3], 0, 0, 0);
        }
        const floatx4 a01 = acc[0] + acc[1];
        const floatx4 a23 = acc[2] + acc[3];
        const floatx4 av  = a01 + a23;

        // ---- epilogue: transpose C via LDS, fused cell update ----
        #pragma unroll
        for (int r = 0; r < 4; ++r) G[wid * 16 + q * 4 + r][cm] = av[r];
        __syncthreads();

        const float4 g4 = *(const float4*)&G[eb][jl * 4];
        const float ig = 1.f / (1.f + expf(-(g4.x + bias4.x)));
        const float fg = 1.f / (1.f + expf(-(g4.y + bias4.y)));
        const float og = 1.f / (1.f + expf(-(g4.z + bias4.z)));
        const float ct = tanhf(g4.w + bias4.w);
        const float cn = fg * c_reg + ig * ct;
        c_reg = cn;
        const float hv = og * tanhf(cn);
        hnxt[eb * H + jg] = (__bf16)hv;
        if (t == T - 1) hfin[eb * H + jg] = hv;

        __syncthreads();  // all G reads done + hnxt stores drained (vmcnt0 at barrier)

        // ---- arrive (release h), then overlap t+1's x-part with the wait ----
        if (tid == 0) {
            __builtin_amdgcn_fence(__ATOMIC_RELEASE, "agent");  // write back L2
            const unsigned old = __hip_atomic_fetch_add(&bar->cnt, 1u, __ATOMIC_RELAXED,
                                                        __HIP_MEMORY_SCOPE_AGENT);
            if (old == NBLK - 1) {
                __hip_atomic_store(&bar->cnt, 0u, __ATOMIC_RELAXED, __HIP_MEMORY_SCOPE_AGENT);
                __hip_atomic_store(&bar->flag, (unsigned)(t + 1), __ATOMIC_RELEASE,
                                   __HIP_MEMORY_SCOPE_AGENT);
            }
        }
        if (t + 1 < T) do_xpart(t + 1);
    }
}

// out[b,o] = h[b,:] . Why[o,:] + bhy[o]
__global__ __launch_bounds__(256) void out_gemm(
    const float* __restrict__ h, const float* __restrict__ Why,
    const float* __restrict__ bhy, float* __restrict__ out)
{
    const int idx = blockIdx.x * 256 + threadIdx.x;
    if (idx >= B * O) return;
    const int b = idx / O;
    const int o = idx % O;
    const float4* hv = (const float4*)&h[(size_t)b * H];
    const float4* wv = (const float4*)&Why[(size_t)o * H];
    float s = 0.f;
    #pragma unroll 4
    for (int k = 0; k < H / 4; ++k) {
        const float4 a = hv[k];
        const float4 w = wv[k];
        s += a.x * w.x + a.y * w.y + a.z * w.z + a.w * w.w;
    }
    out[idx] = s + bhy[o];
}

extern "C" void kernel_launch(void* const* d_in, const int* in_sizes, int n_in,
                              void* d_out, int out_size, void* d_ws, size_t ws_size,
                              hipStream_t stream) {
    const float* x   = (const float*)d_in[0];
    const float* Wx  = (const float*)d_in[1];
    const float* bx  = (const float*)d_in[2];
    const float* Wh  = (const float*)d_in[3];
    const float* bh  = (const float*)d_in[4];
    const float* Why = (const float*)d_in[5];
    const float* bhy = (const float*)d_in[6];
    float* out = (float*)d_out;

    // ws layout (13.12 MB total, < 13.6 MB proven safe):
    // Wc 12,582,912 | bias 16,384 | hb0 131,072 | bar 256 | hb1 131,072 | hfin 262,144
    char* ws = (char*)d_ws;
    __bf16* Wc   = (__bf16*)ws;
    float*  bias = (float*)(ws + 12582912);
    __bf16* hb0  = (__bf16*)(ws + 12599296);
    GBar*   bar  = (GBar*)  (ws + 12730368);
    __bf16* hb1  = (__bf16*)(ws + 12730624);
    float*  hfin = (float*) (ws + 12861696);

    // zero hb0 + barrier (contiguous region)
    hipMemsetAsync(ws + 12599296, 0, 131072 + 256, stream);
    convert_w<<<3072, 256, 0, stream>>>(Wx, Wh, Wc);
    make_bias<<<16, 256, 0, stream>>>(bx, bh, bias);

    lstm_persistent<<<NBLK, 256, 0, stream>>>(x, Wc, bias, hb0, hb1, hfin, bar);

    out_gemm<<<(B * O + 255) / 256, 256, 0, stream>>>(hfin, Why, bhy, out);
}

// Round 4
// 9880.773 us; speedup vs baseline: 3.4337x; 1.1292x over previous
//
#include <hip/hip_runtime.h>
#include <hip/hip_bf16.h>
#include <math.h>

// Problem constants: T=512, B=64, D=512, H=1024, O=512
constexpr int T = 512;
constexpr int B = 64;
constexpr int D = 512;
constexpr int H = 1024;
constexpr int O = 512;
constexpr int NBLK = 128;          // persistent blocks, 1 per CU (96KB LDS)
constexpr int COLS = 32;           // gate-cols per block (8 hidden j's x 4 gates)
constexpr int KCH  = (D + H) / 8;  // 192 k-chunks of 8 elems

typedef __attribute__((ext_vector_type(8))) __bf16 bf16x8;
typedef __attribute__((ext_vector_type(4))) float  floatx4;

// Tree barrier: 8 group counters (16 arrivals each) -> root (8) -> flag.
// Each counter on its own 128B line to avoid cross-channel serialization.
struct GBar {
    unsigned grp[8][32];   // grp[g][0] used, rest pad
    unsigned root; unsigned p0[31];
    unsigned flag; unsigned p1[31];
};

// ---------------------------------------------------------------------------
// W' bf16, strip-major: Wc[strip(128)][kchunk(192)][nl(32)][8]; col reorder
// n = j*4+g. k<512 from Wx[g*H+j][k], else Wh[g*H+j][k-512].
// ---------------------------------------------------------------------------
__global__ __launch_bounds__(256) void convert_w(
    const float* __restrict__ Wx, const float* __restrict__ Wh,
    __bf16* __restrict__ Wc)
{
    const int id = blockIdx.x * 256 + threadIdx.x;   // 128*192*32 = 786432
    if (id >= NBLK * KCH * COLS) return;
    const int nl     = id & 31;
    const int kchunk = (id >> 5) % KCH;
    const int strip  = id / (KCH * COLS);
    const int n = strip * COLS + nl;
    const int j = n >> 2, g = n & 3;
    const int k0 = kchunk * 8;
    const float* src = (k0 < D) ? &Wx[(size_t)(g * H + j) * D + k0]
                                : &Wh[(size_t)(g * H + j) * H + (k0 - D)];
    const float4 a = *(const float4*)src;
    const float4 b = *(const float4*)(src + 4);
    __bf16 t8[8] = {(__bf16)a.x,(__bf16)a.y,(__bf16)a.z,(__bf16)a.w,
                    (__bf16)b.x,(__bf16)b.y,(__bf16)b.z,(__bf16)b.w};
    *(uint4*)&Wc[(size_t)id * 8] = *(uint4*)t8;
}

__global__ __launch_bounds__(256) void make_bias(
    const float* __restrict__ bx, const float* __restrict__ bh,
    float* __restrict__ bias)
{
    const int n = blockIdx.x * 256 + threadIdx.x;
    if (n < 4 * H) {
        const int j = n >> 2, g = n & 3;
        bias[n] = bx[g * H + j] + bh[g * H + j];
    }
}

// ---------------------------------------------------------------------------
// Persistent LSTM: 128 blocks x 256 threads (4 waves), 1 block/CU.
// Block owns 32 gate-cols (8 j's); 96KB W-strip in LDS for all 512 steps;
// c in 2 VGPRs/thread; h exchanged via global bf16 + tree barrier per step.
// x-part MFMAs of step t+1 run between arrive and wait (hides barrier).
// ---------------------------------------------------------------------------
__global__ __launch_bounds__(256, 1) void lstm_persistent(
    const float* __restrict__ x,     // [T,B,D] fp32
    const __bf16* __restrict__ Wc,   // strip-major bf16 (read once at start)
    const float* __restrict__ bias,  // [4096] reordered
    __bf16* __restrict__ hb0,        // [B,H] bf16 ping
    __bf16* __restrict__ hb1,        // [B,H] bf16 pong
    float* __restrict__ hfin,        // [B,H] fp32 final h (aliases Wc head)
    GBar* bar)
{
    __shared__ __attribute__((aligned(16))) __bf16 wlds[KCH * COLS * 8]; // 96 KB
    __shared__ __attribute__((aligned(16))) float  G[64][COLS + 4];      // 9.2 KB

    const int tid  = threadIdx.x;
    const int wid  = tid >> 6;     // wave id == m-tile (16 batch rows)
    const int lane = tid & 63;
    const int cm   = lane & 15;
    const int q    = lane >> 4;
    const int n0   = blockIdx.x * COLS;

    // ---- one-time: W strip -> LDS (6144 x 16B contiguous) ----
    {
        const uint4* wsrc = (const uint4*)(Wc + (size_t)blockIdx.x * KCH * COLS * 8);
        uint4* wdst = (uint4*)wlds;
        for (int i = tid; i < KCH * COLS; i += 256) wdst[i] = wsrc[i];
    }
    // epilogue mapping: thread owns (b=eb, j = jbase, jbase+1); c in registers
    const int eb = tid >> 2;
    const int p  = tid & 3;
    const int jbase = (n0 >> 2) + p * 2;
    const float4 bias0 = *(const float4*)&bias[n0 + p * 8];
    const float4 bias1 = *(const float4*)&bias[n0 + p * 8 + 4];
    float c0 = 0.f, c1 = 0.f;
    __syncthreads();

    const float* xrow = x + (size_t)(wid * 16 + cm) * D + q * 8;
    const int    hoff = (wid * 16 + cm) * H + q * 8;
    const __bf16* wl  = wlds + (q * 32 + cm) * 8;  // + s*1024 (+128 for strip1)

    floatx4 acc[2][2];  // [strip][k-parity]

    auto do_xpart = [&](int tt) {   // K = 0..511 (h-independent)
        acc[0][0] = (floatx4){0,0,0,0}; acc[0][1] = (floatx4){0,0,0,0};
        acc[1][0] = (floatx4){0,0,0,0}; acc[1][1] = (floatx4){0,0,0,0};
        const float* xr = xrow + (size_t)tt * (B * D);
        #pragma unroll
        for (int s = 0; s < 16; ++s) {
            const float4 a0 = *(const float4*)(xr + s * 32);
            const float4 a1 = *(const float4*)(xr + s * 32 + 4);
            const bf16x8 af = {(__bf16)a0.x,(__bf16)a0.y,(__bf16)a0.z,(__bf16)a0.w,
                               (__bf16)a1.x,(__bf16)a1.y,(__bf16)a1.z,(__bf16)a1.w};
            const bf16x8 b0 = *(const bf16x8*)(wl + s * 1024);
            const bf16x8 b1 = *(const bf16x8*)(wl + s * 1024 + 128);
            acc[0][s & 1] = __builtin_amdgcn_mfma_f32_16x16x32_bf16(af, b0, acc[0][s & 1], 0, 0, 0);
            acc[1][s & 1] = __builtin_amdgcn_mfma_f32_16x16x32_bf16(af, b1, acc[1][s & 1], 0, 0, 0);
        }
    };

    do_xpart(0);

    for (int t = 0; t < T; ++t) {
        const __bf16* hcur = (t & 1) ? hb1 : hb0;
        __bf16*       hnxt = (t & 1) ? hb0 : hb1;

        // ---- wait for step t-1's h ----
        if (t > 0) {
            if (tid == 0) {
                while (__hip_atomic_load(&bar->flag, __ATOMIC_RELAXED,
                                         __HIP_MEMORY_SCOPE_AGENT) < (unsigned)t)
                    __builtin_amdgcn_s_sleep(1);
            }
            __syncthreads();
            __builtin_amdgcn_fence(__ATOMIC_ACQUIRE, "agent");
        }

        // ---- h-part: K = 512..1535 ----
        const __bf16* hr = hcur + hoff;
        #pragma unroll
        for (int s = 0; s < 32; ++s) {
            const bf16x8 af = *(const bf16x8*)(hr + s * 32);
            const bf16x8 b0 = *(const bf16x8*)(wl + 16384 + s * 1024);
            const bf16x8 b1 = *(const bf16x8*)(wl + 16384 + s * 1024 + 128);
            acc[0][s & 1] = __builtin_amdgcn_mfma_f32_16x16x32_bf16(af, b0, acc[0][s & 1], 0, 0, 0);
            acc[1][s & 1] = __builtin_amdgcn_mfma_f32_16x16x32_bf16(af, b1, acc[1][s & 1], 0, 0, 0);
        }
        const floatx4 av0 = acc[0][0] + acc[0][1];
        const floatx4 av1 = acc[1][0] + acc[1][1];

        // ---- transpose C via LDS ----
        #pragma unroll
        for (int r = 0; r < 4; ++r) {
            G[wid * 16 + q * 4 + r][cm]      = av0[r];
            G[wid * 16 + q * 4 + r][16 + cm] = av1[r];
        }
        __syncthreads();

        // ---- fused cell update: 2 (b,j) elems per thread ----
        const float4 g0 = *(const float4*)&G[eb][p * 8];
        const float4 g1 = *(const float4*)&G[eb][p * 8 + 4];
        const float i0 = 1.f / (1.f + expf(-(g0.x + bias0.x)));
        const float f0 = 1.f / (1.f + expf(-(g0.y + bias0.y)));
        const float o0 = 1.f / (1.f + expf(-(g0.z + bias0.z)));
        const float t0 = tanhf(g0.w + bias0.w);
        const float i1 = 1.f / (1.f + expf(-(g1.x + bias1.x)));
        const float f1 = 1.f / (1.f + expf(-(g1.y + bias1.y)));
        const float o1 = 1.f / (1.f + expf(-(g1.z + bias1.z)));
        const float t1 = tanhf(g1.w + bias1.w);
        c0 = f0 * c0 + i0 * t0;
        c1 = f1 * c1 + i1 * t1;
        const float hv0 = o0 * tanhf(c0);
        const float hv1 = o1 * tanhf(c1);
        const int hi = eb * H + jbase;
        __bf16 hp[2] = {(__bf16)hv0, (__bf16)hv1};
        *(unsigned*)&hnxt[hi] = *(unsigned*)hp;
        if (t == T - 1) { hfin[hi] = hv0; hfin[hi + 1] = hv1; }

        __syncthreads();  // G reads done + all threads' h stores vmcnt-drained

        // ---- arrive: release h, tree barrier; then overlap t+1 x-part ----
        if (tid == 0) {
            __builtin_amdgcn_fence(__ATOMIC_RELEASE, "agent");  // wbl2: publish h
            const int g = blockIdx.x >> 4;
            const unsigned old = __hip_atomic_fetch_add(&bar->grp[g][0], 1u,
                                    __ATOMIC_RELAXED, __HIP_MEMORY_SCOPE_AGENT);
            if (old == 16u * (unsigned)(t + 1) - 1u) {
                // acquire the group (sync with members' release fences)
                while (__hip_atomic_load(&bar->grp[g][0], __ATOMIC_ACQUIRE,
                                         __HIP_MEMORY_SCOPE_AGENT) < 16u * (unsigned)(t + 1)) {}
                const unsigned r = __hip_atomic_fetch_add(&bar->root, 1u,
                                    __ATOMIC_RELEASE, __HIP_MEMORY_SCOPE_AGENT);
                if (r == 8u * (unsigned)(t + 1) - 1u) {
                    while (__hip_atomic_load(&bar->root, __ATOMIC_ACQUIRE,
                                             __HIP_MEMORY_SCOPE_AGENT) < 8u * (unsigned)(t + 1)) {}
                    __hip_atomic_store(&bar->flag, (unsigned)(t + 1),
                                       __ATOMIC_RELEASE, __HIP_MEMORY_SCOPE_AGENT);
                }
            }
        }
        if (t + 1 < T) do_xpart(t + 1);
    }
}

// out[b,o] = h[b,:] . Why[o,:] + bhy[o]
__global__ __launch_bounds__(256) void out_gemm(
    const float* __restrict__ h, const float* __restrict__ Why,
    const float* __restrict__ bhy, float* __restrict__ out)
{
    const int idx = blockIdx.x * 256 + threadIdx.x;
    if (idx >= B * O) return;
    const int b = idx / O;
    const int o = idx % O;
    const float4* hv = (const float4*)&h[(size_t)b * H];
    const float4* wv = (const float4*)&Why[(size_t)o * H];
    float s = 0.f;
    #pragma unroll 4
    for (int k = 0; k < H / 4; ++k) {
        const float4 a = hv[k];
        const float4 w = wv[k];
        s += a.x * w.x + a.y * w.y + a.z * w.z + a.w * w.w;
    }
    out[idx] = s + bhy[o];
}

extern "C" void kernel_launch(void* const* d_in, const int* in_sizes, int n_in,
                              void* d_out, int out_size, void* d_ws, size_t ws_size,
                              hipStream_t stream) {
    const float* x   = (const float*)d_in[0];
    const float* Wx  = (const float*)d_in[1];
    const float* bx  = (const float*)d_in[2];
    const float* Wh  = (const float*)d_in[3];
    const float* bh  = (const float*)d_in[4];
    const float* Why = (const float*)d_in[5];
    const float* bhy = (const float*)d_in[6];
    float* out = (float*)d_out;

    // ws layout (12,863,488 B total, < 13.12 MB proven):
    // Wc 12,582,912 | bias 16,384 | hb0 131,072 | bar 2,048 | hb1 131,072
    // hfin (256 KB fp32) ALIASES Wc[0:262144): Wc global is read only during
    // the one-time LDS stage, long before any block reaches t=T-1 (511
    // barriers in between) -> safe overlap.
    char* ws = (char*)d_ws;
    __bf16* Wc   = (__bf16*)ws;
    float*  bias = (float*)(ws + 12582912);
    __bf16* hb0  = (__bf16*)(ws + 12599296);
    GBar*   bar  = (GBar*)  (ws + 12730368);
    __bf16* hb1  = (__bf16*)(ws + 12732416);
    float*  hfin = (float*)ws;

    // zero hb0 + barrier (contiguous)
    hipMemsetAsync(ws + 12599296, 0, 131072 + 2048, stream);
    convert_w<<<3072, 256, 0, stream>>>(Wx, Wh, Wc);
    make_bias<<<16, 256, 0, stream>>>(bx, bh, bias);

    lstm_persistent<<<NBLK, 256, 0, stream>>>(x, Wc, bias, hb0, hb1, hfin, bar);

    out_gemm<<<(B * O + 255) / 256, 256, 0, stream>>>(hfin, Why, bhy, out);
}

// Round 5
// 7691.754 us; speedup vs baseline: 4.4109x; 1.2846x over previous
//
#include <hip/hip_runtime.h>
#include <hip/hip_bf16.h>
#include <math.h>

// Problem constants: T=512, B=64, D=512, H=1024, O=512
constexpr int T = 512;
constexpr int B = 64;
constexpr int D = 512;
constexpr int H = 1024;
constexpr int O = 512;
constexpr int NBLK = 128;          // persistent blocks, 1 per CU (96KB LDS)
constexpr int COLS = 32;           // gate-cols per block (8 hidden j's x 4 gates)
constexpr int KCH  = (D + H) / 8;  // 192 k-chunks of 8 elems

typedef __attribute__((ext_vector_type(8))) __bf16 bf16x8;
typedef __attribute__((ext_vector_type(4))) float  floatx4;

// Tree barrier: 8 group counters (16 arrivals each) -> root (8) -> flag.
// All relaxed atomics; h visibility is handled by cache-bypassing h ops.
struct GBar {
    unsigned grp[8][32];   // grp[g][0] used, rest pad (128B lines)
    unsigned root; unsigned p0[31];
    unsigned flag; unsigned p1[31];
};

// ---------------------------------------------------------------------------
// W' bf16, strip-major: Wc[strip(128)][kchunk(192)][nl(32)][8]; col reorder
// n = j*4+g. k<512 from Wx[g*H+j][k], else Wh[g*H+j][k-512].
// ---------------------------------------------------------------------------
__global__ __launch_bounds__(256) void convert_w(
    const float* __restrict__ Wx, const float* __restrict__ Wh,
    __bf16* __restrict__ Wc)
{
    const int id = blockIdx.x * 256 + threadIdx.x;   // 128*192*32 = 786432
    if (id >= NBLK * KCH * COLS) return;
    const int nl     = id & 31;
    const int kchunk = (id >> 5) % KCH;
    const int strip  = id / (KCH * COLS);
    const int n = strip * COLS + nl;
    const int j = n >> 2, g = n & 3;
    const int k0 = kchunk * 8;
    const float* src = (k0 < D) ? &Wx[(size_t)(g * H + j) * D + k0]
                                : &Wh[(size_t)(g * H + j) * H + (k0 - D)];
    const float4 a = *(const float4*)src;
    const float4 b = *(const float4*)(src + 4);
    __bf16 t8[8] = {(__bf16)a.x,(__bf16)a.y,(__bf16)a.z,(__bf16)a.w,
                    (__bf16)b.x,(__bf16)b.y,(__bf16)b.z,(__bf16)b.w};
    *(uint4*)&Wc[(size_t)id * 8] = *(uint4*)t8;
}

__global__ __launch_bounds__(256) void make_bias(
    const float* __restrict__ bx, const float* __restrict__ bh,
    float* __restrict__ bias)
{
    const int n = blockIdx.x * 256 + threadIdx.x;
    if (n < 4 * H) {
        const int j = n >> 2, g = n & 3;
        bias[n] = bx[g * H + j] + bh[g * H + j];
    }
}

// ---------------------------------------------------------------------------
// Persistent LSTM, FENCE-FREE: 128 blocks x 256 threads, 1 block/CU.
// h is published with relaxed agent-scope atomic stores (write-through to the
// coherence point) and read with relaxed agent-scope atomic loads (bypass
// L1/L2) -> no buffer_wbl2 / buffer_inv tag-walks per step, which round 4
// identified as the ~17 us/step floor. Everything else (W strip in LDS,
// c in VGPRs, x-part overlap with barrier wait) unchanged.
// ---------------------------------------------------------------------------
__global__ __launch_bounds__(256, 1) void lstm_persistent(
    const float* __restrict__ x,     // [T,B,D] fp32
    const __bf16* __restrict__ Wc,   // strip-major bf16 (read once at start)
    const float* __restrict__ bias,  // [4096] reordered
    __bf16* __restrict__ hb0,        // [B,H] bf16 ping
    __bf16* __restrict__ hb1,        // [B,H] bf16 pong
    float* __restrict__ hfin,        // [B,H] fp32 final h (aliases Wc head)
    GBar* bar)
{
    __shared__ __attribute__((aligned(16))) __bf16 wlds[KCH * COLS * 8]; // 96 KB
    __shared__ __attribute__((aligned(16))) float  G[64][COLS + 4];      // 9.2 KB

    const int tid  = threadIdx.x;
    const int wid  = tid >> 6;     // wave id == m-tile (16 batch rows)
    const int lane = tid & 63;
    const int cm   = lane & 15;
    const int q    = lane >> 4;
    const int n0   = blockIdx.x * COLS;

    // ---- one-time: W strip -> LDS (6144 x 16B contiguous) ----
    {
        const uint4* wsrc = (const uint4*)(Wc + (size_t)blockIdx.x * KCH * COLS * 8);
        uint4* wdst = (uint4*)wlds;
        for (int i = tid; i < KCH * COLS; i += 256) wdst[i] = wsrc[i];
    }
    // epilogue mapping: thread owns (b=eb, j = jbase, jbase+1); c in registers
    const int eb = tid >> 2;
    const int p  = tid & 3;
    const int jbase = (n0 >> 2) + p * 2;
    const float4 bias0 = *(const float4*)&bias[n0 + p * 8];
    const float4 bias1 = *(const float4*)&bias[n0 + p * 8 + 4];
    float c0 = 0.f, c1 = 0.f;
    __syncthreads();

    const float* xrow = x + (size_t)(wid * 16 + cm) * D + q * 8;
    const int    hoff = (wid * 16 + cm) * H + q * 8;
    const __bf16* wl  = wlds + (q * 32 + cm) * 8;  // + s*1024 (+128 for strip1)

    floatx4 acc[2][2];  // [strip][k-parity]

    auto do_xpart = [&](int tt) {   // K = 0..511 (h-independent)
        acc[0][0] = (floatx4){0,0,0,0}; acc[0][1] = (floatx4){0,0,0,0};
        acc[1][0] = (floatx4){0,0,0,0}; acc[1][1] = (floatx4){0,0,0,0};
        const float* xr = xrow + (size_t)tt * (B * D);
        #pragma unroll
        for (int s = 0; s < 16; ++s) {
            const float4 a0 = *(const float4*)(xr + s * 32);
            const float4 a1 = *(const float4*)(xr + s * 32 + 4);
            const bf16x8 af = {(__bf16)a0.x,(__bf16)a0.y,(__bf16)a0.z,(__bf16)a0.w,
                               (__bf16)a1.x,(__bf16)a1.y,(__bf16)a1.z,(__bf16)a1.w};
            const bf16x8 b0 = *(const bf16x8*)(wl + s * 1024);
            const bf16x8 b1 = *(const bf16x8*)(wl + s * 1024 + 128);
            acc[0][s & 1] = __builtin_amdgcn_mfma_f32_16x16x32_bf16(af, b0, acc[0][s & 1], 0, 0, 0);
            acc[1][s & 1] = __builtin_amdgcn_mfma_f32_16x16x32_bf16(af, b1, acc[1][s & 1], 0, 0, 0);
        }
    };

    do_xpart(0);

    for (int t = 0; t < T; ++t) {
        const __bf16* hcur = (t & 1) ? hb1 : hb0;
        __bf16*       hnxt = (t & 1) ? hb0 : hb1;

        // ---- wait for step t-1's h (no fence: h ops bypass caches) ----
        if (t > 0) {
            if (tid == 0) {
                while (__hip_atomic_load(&bar->flag, __ATOMIC_RELAXED,
                                         __HIP_MEMORY_SCOPE_AGENT) < (unsigned)t)
                    __builtin_amdgcn_s_sleep(1);
            }
            __syncthreads();
        }

        // ---- h-part: K = 512..1535; h read via coherence-point loads ----
        const unsigned long long* hr =
            (const unsigned long long*)(hcur + hoff);   // 16B-aligned
        #pragma unroll
        for (int s = 0; s < 32; ++s) {
            union { unsigned long long u[2]; bf16x8 v; } hf;
            hf.u[0] = __hip_atomic_load(hr + s * 8,     __ATOMIC_RELAXED,
                                        __HIP_MEMORY_SCOPE_AGENT);
            hf.u[1] = __hip_atomic_load(hr + s * 8 + 1, __ATOMIC_RELAXED,
                                        __HIP_MEMORY_SCOPE_AGENT);
            const bf16x8 b0 = *(const bf16x8*)(wl + 16384 + s * 1024);
            const bf16x8 b1 = *(const bf16x8*)(wl + 16384 + s * 1024 + 128);
            acc[0][s & 1] = __builtin_amdgcn_mfma_f32_16x16x32_bf16(hf.v, b0, acc[0][s & 1], 0, 0, 0);
            acc[1][s & 1] = __builtin_amdgcn_mfma_f32_16x16x32_bf16(hf.v, b1, acc[1][s & 1], 0, 0, 0);
        }
        const floatx4 av0 = acc[0][0] + acc[0][1];
        const floatx4 av1 = acc[1][0] + acc[1][1];

        // ---- transpose C via LDS ----
        #pragma unroll
        for (int r = 0; r < 4; ++r) {
            G[wid * 16 + q * 4 + r][cm]      = av0[r];
            G[wid * 16 + q * 4 + r][16 + cm] = av1[r];
        }
        __syncthreads();

        // ---- fused cell update: 2 (b,j) elems per thread ----
        const float4 g0 = *(const float4*)&G[eb][p * 8];
        const float4 g1 = *(const float4*)&G[eb][p * 8 + 4];
        const float i0 = 1.f / (1.f + expf(-(g0.x + bias0.x)));
        const float f0 = 1.f / (1.f + expf(-(g0.y + bias0.y)));
        const float o0 = 1.f / (1.f + expf(-(g0.z + bias0.z)));
        const float t0 = tanhf(g0.w + bias0.w);
        const float i1 = 1.f / (1.f + expf(-(g1.x + bias1.x)));
        const float f1 = 1.f / (1.f + expf(-(g1.y + bias1.y)));
        const float o1 = 1.f / (1.f + expf(-(g1.z + bias1.z)));
        const float t1 = tanhf(g1.w + bias1.w);
        c0 = f0 * c0 + i0 * t0;
        c1 = f1 * c1 + i1 * t1;
        const float hv0 = o0 * tanhf(c0);
        const float hv1 = o1 * tanhf(c1);
        const int hi = eb * H + jbase;
        union { __bf16 h2[2]; unsigned u; } hp;
        hp.h2[0] = (__bf16)hv0; hp.h2[1] = (__bf16)hv1;
        // publish h: write-through to coherence point (no fence needed)
        __hip_atomic_store((unsigned*)&hnxt[hi], hp.u, __ATOMIC_RELAXED,
                           __HIP_MEMORY_SCOPE_AGENT);
        if (t == T - 1) { hfin[hi] = hv0; hfin[hi + 1] = hv1; }

        // all G reads done + every thread's h store vmcnt-drained (compiler
        // emits s_waitcnt vmcnt(0) before s_barrier)
        __syncthreads();

        // ---- arrive (all-relaxed tree), then overlap t+1's x-part ----
        if (tid == 0) {
            const int g = blockIdx.x >> 4;
            const unsigned old = __hip_atomic_fetch_add(&bar->grp[g][0], 1u,
                                    __ATOMIC_RELAXED, __HIP_MEMORY_SCOPE_AGENT);
            if (old == 16u * (unsigned)(t + 1) - 1u) {
                const unsigned r = __hip_atomic_fetch_add(&bar->root, 1u,
                                    __ATOMIC_RELAXED, __HIP_MEMORY_SCOPE_AGENT);
                if (r == 8u * (unsigned)(t + 1) - 1u) {
                    __hip_atomic_store(&bar->flag, (unsigned)(t + 1),
                                       __ATOMIC_RELAXED, __HIP_MEMORY_SCOPE_AGENT);
                }
            }
        }
        if (t + 1 < T) do_xpart(t + 1);
    }
}

// out[b,o] = h[b,:] . Why[o,:] + bhy[o]
__global__ __launch_bounds__(256) void out_gemm(
    const float* __restrict__ h, const float* __restrict__ Why,
    const float* __restrict__ bhy, float* __restrict__ out)
{
    const int idx = blockIdx.x * 256 + threadIdx.x;
    if (idx >= B * O) return;
    const int b = idx / O;
    const int o = idx % O;
    const float4* hv = (const float4*)&h[(size_t)b * H];
    const float4* wv = (const float4*)&Why[(size_t)o * H];
    float s = 0.f;
    #pragma unroll 4
    for (int k = 0; k < H / 4; ++k) {
        const float4 a = hv[k];
        const float4 w = wv[k];
        s += a.x * w.x + a.y * w.y + a.z * w.z + a.w * w.w;
    }
    out[idx] = s + bhy[o];
}

extern "C" void kernel_launch(void* const* d_in, const int* in_sizes, int n_in,
                              void* d_out, int out_size, void* d_ws, size_t ws_size,
                              hipStream_t stream) {
    const float* x   = (const float*)d_in[0];
    const float* Wx  = (const float*)d_in[1];
    const float* bx  = (const float*)d_in[2];
    const float* Wh  = (const float*)d_in[3];
    const float* bh  = (const float*)d_in[4];
    const float* Why = (const float*)d_in[5];
    const float* bhy = (const float*)d_in[6];
    float* out = (float*)d_out;

    // ws layout (12,863,488 B total):
    // Wc 12,582,912 | bias 16,384 | hb0 131,072 | bar 2,048 | hb1 131,072
    // hfin (256 KB fp32) aliases Wc[0:262144) — Wc is only read during the
    // one-time LDS stage, 511 barriers before any t=T-1 write. Safe.
    char* ws = (char*)d_ws;
    __bf16* Wc   = (__bf16*)ws;
    float*  bias = (float*)(ws + 12582912);
    __bf16* hb0  = (__bf16*)(ws + 12599296);
    GBar*   bar  = (GBar*)  (ws + 12730368);
    __bf16* hb1  = (__bf16*)(ws + 12732416);
    float*  hfin = (float*)ws;

    // zero hb0 + barrier (contiguous)
    hipMemsetAsync(ws + 12599296, 0, 131072 + 2048, stream);
    convert_w<<<3072, 256, 0, stream>>>(Wx, Wh, Wc);
    make_bias<<<16, 256, 0, stream>>>(bx, bh, bias);

    lstm_persistent<<<NBLK, 256, 0, stream>>>(x, Wc, bias, hb0, hb1, hfin, bar);

    out_gemm<<<(B * O + 255) / 256, 256, 0, stream>>>(hfin, Why, bhy, out);
}